// Round 8
// baseline (140.382 us; speedup 1.0000x reference)
//
#include <hip/hip_runtime.h>

#define CMAX    1000
#define FIXS    1048576.0f    // 2^20 fixed-point scale
#define INVFIXS (1.0f / 1048576.0f)
#define NB_HIST 256
#define NB_BLD  128
#define SPAN    64            // sorted rows per wave in segsum

// ---------------------------------------------------------------------------
// Pass A: label histogram (LDS-privatized) -> tot[c]
// ---------------------------------------------------------------------------
__global__ __launch_bounds__(256) void hist_kernel(
    const int* __restrict__ l, int* __restrict__ tot, int B)
{
    __shared__ int h[CMAX];
    for (int i = threadIdx.x; i < CMAX; i += 256) h[i] = 0;
    __syncthreads();
    const int per  = (B + gridDim.x - 1) / gridDim.x;
    const int base = blockIdx.x * per;
    const int end  = min(B, base + per);
    for (int i = base + threadIdx.x; i < end; i += 256)
        atomicAdd(&h[l[i]], 1);
    __syncthreads();
    for (int i = threadIdx.x; i < CMAX; i += 256) {
        const int v = h[i];
        if (v) atomicAdd(&tot[i], v);
    }
}

// ---------------------------------------------------------------------------
// Pass B: exclusive scan of tot -> offs[0..C] (pristine), gcur[c] (working
// reservation cursors), cnt_i[c] = tot[c].
// ---------------------------------------------------------------------------
__global__ __launch_bounds__(1024) void scan_kernel(
    const int* __restrict__ tot, int* __restrict__ offs,
    int* __restrict__ gcur, int* __restrict__ cnt_i, int C, int B)
{
    __shared__ int s[1024];
    const int t = threadIdx.x;
    const int v = (t < C) ? tot[t] : 0;
    s[t] = v;
    if (t < C) cnt_i[t] = v;
    for (int off = 1; off < 1024; off <<= 1) {
        __syncthreads();
        const int u = (t >= off) ? s[t - off] : 0;
        __syncthreads();
        s[t] += u;
    }
    __syncthreads();
    if (t < C) {
        const int e = s[t] - v;       // exclusive prefix
        offs[t] = e;
        gcur[t] = e;
    }
    if (t == 0) offs[C] = B;
}

// ---------------------------------------------------------------------------
// Pass C: two-level permutation build. Per block: LDS histogram of its
// label range, ONE global reservation atomic per present class, then
// LDS-cursor placement.
// ---------------------------------------------------------------------------
__global__ __launch_bounds__(1024) void build_kernel(
    const int* __restrict__ l, int* __restrict__ gcur,
    int* __restrict__ perm, int B)
{
    __shared__ int lhist[CMAX];
    __shared__ int lbase[CMAX];
    const int per  = (B + gridDim.x - 1) / gridDim.x;
    const int base = blockIdx.x * per;
    const int end  = min(B, base + per);

    for (int i = threadIdx.x; i < CMAX; i += 1024) lhist[i] = 0;
    __syncthreads();
    for (int i = base + threadIdx.x; i < end; i += 1024)
        atomicAdd(&lhist[l[i]], 1);
    __syncthreads();
    for (int c = threadIdx.x; c < CMAX; c += 1024) {
        const int n = lhist[c];
        lbase[c] = n ? atomicAdd(&gcur[c], n) : 0;
        lhist[c] = 0;                 // reuse as local cursor
    }
    __syncthreads();
    for (int i = base + threadIdx.x; i < end; i += 1024) {
        const int c = l[i];
        const int r = atomicAdd(&lhist[c], 1);
        perm[lbase[c] + r] = i;
    }
}

// ---------------------------------------------------------------------------
// Pass D: segment-sum over sorted order, 4-DEEP MLP version.
// One wave per SPAN=64 sorted rows; each superstep issues FOUR independent
// 1KB row loads (named registers -- no runtime indexing) before consuming
// them, quadrupling outstanding bytes per wave vs the 1-deep R7 loop.
// Class boundaries via binary search on pristine offs[]; register
// fixed-point accumulation; rare run-flushes via native int atomics.
// ---------------------------------------------------------------------------
__global__ __launch_bounds__(256) void segsum_kernel(
    const float* __restrict__ x, const int* __restrict__ perm,
    const int* __restrict__ offs, int* __restrict__ sums_i,
    int B, int D, int C)
{
    const int lane = threadIdx.x & 63;
    const int wid  = (int)((blockIdx.x * blockDim.x + threadIdx.x) >> 6);
    const int p0 = wid * SPAN;
    if (p0 >= B) return;
    const int n  = min(SPAN, B - p0);
    const int DV = D >> 2;
    const float4* __restrict__ x4 = (const float4*)x;

    // this wave's perm entries: one coalesced load, broadcast via shfl
    const int myidx = (p0 + lane < B) ? perm[p0 + lane] : 0;

    // binary search: cur = max c with offs[c] <= p0
    int lo = 0, hi = C - 1;
    while (lo < hi) {
        const int mid = (lo + hi + 1) >> 1;
        if (offs[mid] <= p0) lo = mid; else hi = mid - 1;
    }
    int cur = lo;
    int nxt = offs[cur + 1];

    int ax = 0, ay = 0, az = 0, aw = 0;

#define FLUSH_TO(pp)                                                    \
    while ((pp) >= nxt) {                                               \
        if (ax | ay | az | aw) {                                        \
            int* dst_ = sums_i + (size_t)cur * D + (lane << 2);         \
            atomicAdd(dst_ + 0, ax);                                    \
            atomicAdd(dst_ + 1, ay);                                    \
            atomicAdd(dst_ + 2, az);                                    \
            atomicAdd(dst_ + 3, aw);                                    \
            ax = ay = az = aw = 0;                                      \
        }                                                               \
        ++cur;                                                          \
        nxt = offs[cur + 1];                                            \
    }
#define ACCUM(vv)                                                       \
    ax += __float2int_rn((vv).x * FIXS);                                \
    ay += __float2int_rn((vv).y * FIXS);                                \
    az += __float2int_rn((vv).z * FIXS);                                \
    aw += __float2int_rn((vv).w * FIXS);

    int it = 0;
    for (; it + 4 <= n; it += 4) {
        // four independent row loads in flight
        const int i0 = __shfl(myidx, it + 0, 64);
        const int i1 = __shfl(myidx, it + 1, 64);
        const int i2 = __shfl(myidx, it + 2, 64);
        const int i3 = __shfl(myidx, it + 3, 64);
        const float4 v0 = x4[(size_t)i0 * DV + lane];
        const float4 v1 = x4[(size_t)i1 * DV + lane];
        const float4 v2 = x4[(size_t)i2 * DV + lane];
        const float4 v3 = x4[(size_t)i3 * DV + lane];
        FLUSH_TO(p0 + it + 0); ACCUM(v0);
        FLUSH_TO(p0 + it + 1); ACCUM(v1);
        FLUSH_TO(p0 + it + 2); ACCUM(v2);
        FLUSH_TO(p0 + it + 3); ACCUM(v3);
    }
    for (; it < n; ++it) {
        const int i0 = __shfl(myidx, it, 64);
        const float4 v0 = x4[(size_t)i0 * DV + lane];
        FLUSH_TO(p0 + it); ACCUM(v0);
    }
    int* dst = sums_i + (size_t)cur * D + (lane << 2);
    atomicAdd(dst + 0, ax);
    atomicAdd(dst + 1, ay);
    atomicAdd(dst + 2, az);
    atomicAdd(dst + 3, aw);
#undef FLUSH_TO
#undef ACCUM
}

// ---------------------------------------------------------------------------
// block-wide sum over 256 threads (4 waves); result broadcast to all threads
// ---------------------------------------------------------------------------
__device__ __forceinline__ float block_reduce_sum_256(float v, float* sbuf) {
    #pragma unroll
    for (int o = 32; o > 0; o >>= 1) v += __shfl_down(v, o, 64);
    __syncthreads();                 // protect sbuf across repeated calls
    if ((threadIdx.x & 63) == 0) sbuf[threadIdx.x >> 6] = v;
    __syncthreads();
    return sbuf[0] + sbuf[1] + sbuf[2] + sbuf[3];
}

// ---------------------------------------------------------------------------
// Per-class momentum update + L2 renorm + squared distance.
// One block (256 threads == D) per class.
// ---------------------------------------------------------------------------
__global__ __launch_bounds__(256) void update_kernel(
    const int* __restrict__ sums_i, const int* __restrict__ cnt_i,
    const float* __restrict__ cimg, const float* __restrict__ cskt,
    float* __restrict__ sq_out, float* __restrict__ pres_out, int C, int D)
{
    __shared__ float sbuf[4];
    __shared__ float cshare;
    const int c = blockIdx.x;
    const int t = threadIdx.x;

    const float ssum = (float)sums_i[(size_t)c * D + t] * INVFIXS;
    if (t == 0) cshare = (float)cnt_i[c];
    __syncthreads();
    const float cnt = cshare;

    const bool present = cnt > 0.5f;
    const size_t idx = (size_t)c * D + t;
    const float ci = cimg[idx];
    const float cs = cskt[idx];
    const float mean = ssum / fmaxf(cnt, 1.f);
    const float upd = ci * 0.9f + mean * 0.1f;
    const float n2 = block_reduce_sum_256(upd * upd, sbuf);
    const float inv = 1.0f / sqrtf(n2);
    const float newv = present ? upd * inv : ci;
    const float df = newv - cs;
    const float sq = block_reduce_sum_256(df * df, sbuf);
    if (t == 0) {
        sq_out[c]   = present ? sq : 0.f;
        pres_out[c] = present ? 1.f : 0.f;
    }
}

// ---------------------------------------------------------------------------
// Final reduction over classes -> scalar loss
// ---------------------------------------------------------------------------
__global__ __launch_bounds__(256) void finalize_kernel(
    const float* __restrict__ sq, const float* __restrict__ pres,
    float* __restrict__ out, int C)
{
    __shared__ float sbuf[4];
    float ls = 0.f, np = 0.f;
    for (int i = threadIdx.x; i < C; i += 256) {
        ls += sq[i];
        np += pres[i];
    }
    ls = block_reduce_sum_256(ls, sbuf);
    np = block_reduce_sum_256(np, sbuf);
    if (threadIdx.x == 0) out[0] = ls / fmaxf(np, 1.f);
}

extern "C" void kernel_launch(void* const* d_in, const int* in_sizes, int n_in,
                              void* d_out, int out_size, void* d_ws, size_t ws_size,
                              hipStream_t stream) {
    const float* x    = (const float*)d_in[0];
    const int*   l    = (const int*)d_in[1];
    const float* cimg = (const float*)d_in[2];
    const float* cskt = (const float*)d_in[3];

    const int B = in_sizes[1];
    const int D = in_sizes[0] / B;     // 256
    const int C = in_sizes[2] / D;     // 1000

    int* sums_i = (int*)d_ws;                     // [C*D]
    int* tot    = sums_i + (size_t)C * D;         // [C]   (zeroed with sums)
    int* cnt_i  = tot + C;                        // [C]
    int* offs   = cnt_i + C;                      // [C+1]
    int* gcur   = offs + C + 1;                   // [C]
    int* perm   = gcur + C;                       // [B]
    float* sq   = (float*)(perm + B);             // [C]
    float* pres = sq + C;                         // [C]

    // zero sums_i + tot (adjacent) every call (graph-replay safe)
    hipMemsetAsync(sums_i, 0, sizeof(int) * ((size_t)C * D + C), stream);

    hist_kernel<<<NB_HIST, 256, 0, stream>>>(l, tot, B);
    scan_kernel<<<1, 1024, 0, stream>>>(tot, offs, gcur, cnt_i, C, B);
    build_kernel<<<NB_BLD, 1024, 0, stream>>>(l, gcur, perm, B);

    const int waves   = (B + SPAN - 1) / SPAN;
    const int dblocks = (waves + 3) / 4;          // 4 waves per 256-thr block
    segsum_kernel<<<dblocks, 256, 0, stream>>>(x, perm, offs, sums_i, B, D, C);

    update_kernel<<<C, 256, 0, stream>>>(sums_i, cnt_i, cimg, cskt, sq, pres, C, D);
    finalize_kernel<<<1, 256, 0, stream>>>(sq, pres, (float*)d_out, C);
}